// Round 1
// baseline (237.177 us; speedup 1.0000x reference)
//
#include <hip/hip_runtime.h>

// LSTM text classifier: emb-gather -> LSTM(512 steps) -> FC(32->2)
// Plan:
//   K1 build_ptab: ptab[v][g] = dot(emb[v], w_ih[g]) + b_ih[g] + b_hh[g]
//      stored interleaved as float2 {gate l, gate l+64} per lane -> 25.6 MB in d_ws
//   K2 lstm_scan: 1 wave per batch element (1024 waves = 1/SIMD).
//      lane l owns gates l and l+64 (w_hh rows in 64 VGPRs).
//      h broadcast via v_readlane (no LDS round trip); gather prefetched 4 deep.

__device__ __forceinline__ float fast_rcp(float x) {
    return __builtin_amdgcn_rcpf(x);
}
__device__ __forceinline__ float fast_sigmoid(float x) {
    // 1/(1+e^-x); __expf -> v_mul + v_exp_f32
    float e = __expf(-x);
    return fast_rcp(1.0f + e);
}
__device__ __forceinline__ float fast_tanh(float x) {
    // 1 - 2/(e^{2x}+1); handles +/-inf overflow correctly (exp->inf => 1, exp->0 => -1)
    float e = __expf(2.0f * x);
    return fmaf(-2.0f, fast_rcp(1.0f + e), 1.0f);
}

__device__ __forceinline__ float lane_bcast(float v, int srclane) {
    return __uint_as_float(__builtin_amdgcn_readlane(__float_as_uint(v), srclane));
}

// ---------------- K1: projected embedding table ----------------
__global__ __launch_bounds__(64, 1) void build_ptab(
    const float4* __restrict__ emb4, const float4* __restrict__ wih4,
    const float* __restrict__ bih, const float* __restrict__ bhh,
    float2* __restrict__ ptab, int nrows) {
    const int lane = threadIdx.x;

    float w0[32], w1[32];
#pragma unroll
    for (int q = 0; q < 8; ++q) {
        float4 a = wih4[lane * 8 + q];
        float4 b = wih4[(lane + 64) * 8 + q];
        w0[4 * q + 0] = a.x; w0[4 * q + 1] = a.y; w0[4 * q + 2] = a.z; w0[4 * q + 3] = a.w;
        w1[4 * q + 0] = b.x; w1[4 * q + 1] = b.y; w1[4 * q + 2] = b.z; w1[4 * q + 3] = b.w;
    }
    const float bias0 = bih[lane] + bhh[lane];
    const float bias1 = bih[lane + 64] + bhh[lane + 64];

    for (int v = blockIdx.x; v < nrows; v += gridDim.x) {
        float a0 = bias0, a1 = bias1;
#pragma unroll
        for (int q = 0; q < 8; ++q) {
            float4 e = emb4[v * 8 + q];  // wave-uniform -> broadcast from cache
            a0 = fmaf(e.x, w0[4 * q + 0], a0);
            a0 = fmaf(e.y, w0[4 * q + 1], a0);
            a0 = fmaf(e.z, w0[4 * q + 2], a0);
            a0 = fmaf(e.w, w0[4 * q + 3], a0);
            a1 = fmaf(e.x, w1[4 * q + 0], a1);
            a1 = fmaf(e.y, w1[4 * q + 1], a1);
            a1 = fmaf(e.z, w1[4 * q + 2], a1);
            a1 = fmaf(e.w, w1[4 * q + 3], a1);
        }
        ptab[v * 64 + lane] = make_float2(a0, a1);  // coalesced 512B/row
    }
}

// ---------------- K2: LSTM scan, one wave per batch element ----------------
template <bool PTAB>
__global__ __launch_bounds__(64, 1) void lstm_scan(
    const int* __restrict__ x,
    const float2* __restrict__ ptab,
    const float* __restrict__ emb,
    const float* __restrict__ wih,
    const float* __restrict__ bih,
    const float* __restrict__ bhh,
    const float* __restrict__ whh,
    const float* __restrict__ fcw,
    const float* __restrict__ fcb,
    float* __restrict__ out,
    int S) {
    extern __shared__ int xrow[];
    const int b = blockIdx.x;
    const int lane = threadIdx.x;

    // stage this batch element's token ids in LDS (needed for prefetch addressing)
    for (int i = lane; i < S; i += 64) xrow[i] = x[(size_t)b * S + i];
    __syncthreads();

    // recurrent weights: lane l holds w_hh rows l and l+64
    float w0[32], w1[32];
    {
        const float4* whh4 = (const float4*)whh;
#pragma unroll
        for (int q = 0; q < 8; ++q) {
            float4 a = whh4[lane * 8 + q];
            float4 bb = whh4[(lane + 64) * 8 + q];
            w0[4 * q + 0] = a.x; w0[4 * q + 1] = a.y; w0[4 * q + 2] = a.z; w0[4 * q + 3] = a.w;
            w1[4 * q + 0] = bb.x; w1[4 * q + 1] = bb.y; w1[4 * q + 2] = bb.z; w1[4 * q + 3] = bb.w;
        }
    }

    float h = 0.0f, c = 0.0f;

    // one LSTM step given the input-projection pre-activations for this lane's 2 gates
    auto STEP = [&](float a0, float a1) {
        // gates += h @ w_hh^T ; h lives in lanes 0..31, broadcast via readlane (SGPR operand)
#pragma unroll
        for (int j = 0; j < 32; ++j) {
            float hj = lane_bcast(h, j);
            a0 = fmaf(hj, w0[j], a0);
            a1 = fmaf(hj, w1[j], a1);
        }
        // lane k<32 has (i_k, g_k); lane 32+k has (f_k, o_k). Swap halves.
        float b0 = __shfl_xor(a0, 32, 64);
        float b1 = __shfl_xor(a1, 32, 64);
        // lanes 0..31 compute the real update; lanes 32..63 compute bounded garbage (never read)
        float ig = fast_sigmoid(a0);
        float fg = fast_sigmoid(b0);
        float gg = fast_tanh(a1);
        float og = fast_sigmoid(b1);
        c = fmaf(fg, c, ig * gg);
        h = og * fast_tanh(c);
    };

    if (PTAB) {
        auto LOADP = [&](int tt) -> float2 {
            int idx = xrow[(tt < S) ? tt : 0];  // OOB-safe prefetch
            return ptab[idx * 64 + lane];
        };
        // prefetch ring, depth 4, hand-unrolled so everything stays in registers
        float2 p0 = LOADP(0), p1 = LOADP(1), p2 = LOADP(2), p3 = LOADP(3);
        const int S4 = S & ~3;
        for (int t = 0; t < S4; t += 4) {
            STEP(p0.x, p0.y); p0 = LOADP(t + 4);
            STEP(p1.x, p1.y); p1 = LOADP(t + 5);
            STEP(p2.x, p2.y); p2 = LOADP(t + 6);
            STEP(p3.x, p3.y); p3 = LOADP(t + 7);
        }
        const int rem = S & 3;
        if (rem > 0) STEP(p0.x, p0.y);
        if (rem > 1) STEP(p1.x, p1.y);
        if (rem > 2) STEP(p2.x, p2.y);
    } else {
        // fallback: compute input projection on the fly (workspace too small)
        float wi0[32], wi1[32];
        {
            const float4* wih4 = (const float4*)wih;
#pragma unroll
            for (int q = 0; q < 8; ++q) {
                float4 a = wih4[lane * 8 + q];
                float4 bb = wih4[(lane + 64) * 8 + q];
                wi0[4 * q + 0] = a.x; wi0[4 * q + 1] = a.y; wi0[4 * q + 2] = a.z; wi0[4 * q + 3] = a.w;
                wi1[4 * q + 0] = bb.x; wi1[4 * q + 1] = bb.y; wi1[4 * q + 2] = bb.z; wi1[4 * q + 3] = bb.w;
            }
        }
        const float bias0 = bih[lane] + bhh[lane];
        const float bias1 = bih[lane + 64] + bhh[lane + 64];
        const float4* emb4 = (const float4*)emb;

        float4 eA[8], eB[8];
        auto LOADE = [&](int tt, float4* e) {
            int idx = xrow[(tt < S) ? tt : 0];
#pragma unroll
            for (int q = 0; q < 8; ++q) e[q] = emb4[idx * 8 + q];  // uniform
        };
        auto STEPE = [&](const float4* e) {
            float a0 = bias0, a1 = bias1;
#pragma unroll
            for (int q = 0; q < 8; ++q) {
                a0 = fmaf(e[q].x, wi0[4 * q + 0], a0);
                a0 = fmaf(e[q].y, wi0[4 * q + 1], a0);
                a0 = fmaf(e[q].z, wi0[4 * q + 2], a0);
                a0 = fmaf(e[q].w, wi0[4 * q + 3], a0);
                a1 = fmaf(e[q].x, wi1[4 * q + 0], a1);
                a1 = fmaf(e[q].y, wi1[4 * q + 1], a1);
                a1 = fmaf(e[q].z, wi1[4 * q + 2], a1);
                a1 = fmaf(e[q].w, wi1[4 * q + 3], a1);
            }
            STEP(a0, a1);
        };
        LOADE(0, eA);
        int t = 0;
        for (; t + 2 <= S; t += 2) {
            LOADE(t + 1, eB);
            STEPE(eA);
            LOADE(t + 2, eA);
            STEPE(eB);
        }
        if (t < S) STEPE(eA);
    }

    // FC: out[b][n] = sum_k h_k * fc_w[n][k] + fc_b[n]; h valid in lanes 0..31
    float wv0 = fcw[lane & 31];
    float wv1 = fcw[32 + (lane & 31)];
    float p0v = (lane < 32) ? h * wv0 : 0.0f;
    float p1v = (lane < 32) ? h * wv1 : 0.0f;
#pragma unroll
    for (int m = 32; m >= 1; m >>= 1) {
        p0v += __shfl_xor(p0v, m, 64);
        p1v += __shfl_xor(p1v, m, 64);
    }
    if (lane == 0) {
        out[b * 2 + 0] = p0v + fcb[0];
        out[b * 2 + 1] = p1v + fcb[1];
    }
}

extern "C" void kernel_launch(void* const* d_in, const int* in_sizes, int n_in,
                              void* d_out, int out_size, void* d_ws, size_t ws_size,
                              hipStream_t stream) {
    const int* x = (const int*)d_in[0];
    const float* emb = (const float*)d_in[1];
    const float* wih = (const float*)d_in[2];
    const float* whh = (const float*)d_in[3];
    const float* bih = (const float*)d_in[4];
    const float* bhh = (const float*)d_in[5];
    const float* fcw = (const float*)d_in[6];
    const float* fcb = (const float*)d_in[7];
    float* out = (float*)d_out;

    const int B = out_size / 2;          // 1024
    const int S = in_sizes[0] / B;       // 512
    const int nrows = in_sizes[1] / 32;  // 50001 (EMB=32)

    const size_t need = (size_t)nrows * 64 * sizeof(float2);  // 25.6 MB
    const size_t smem = (size_t)S * sizeof(int);

    if (ws_size >= need) {
        float2* ptab = (float2*)d_ws;
        int nb = nrows < 2048 ? nrows : 2048;
        build_ptab<<<nb, 64, 0, stream>>>((const float4*)emb, (const float4*)wih,
                                          bih, bhh, ptab, nrows);
        lstm_scan<true><<<B, 64, smem, stream>>>(x, ptab, emb, wih, bih, bhh, whh,
                                                 fcw, fcb, out, S);
    } else {
        lstm_scan<false><<<B, 64, smem, stream>>>(x, nullptr, emb, wih, bih, bhh, whh,
                                                  fcw, fcb, out, S);
    }
}

// Round 2
// 175.216 us; speedup vs baseline: 1.3536x; 1.3536x over previous
//
#include <hip/hip_runtime.h>

// LSTM text classifier: emb-gather -> LSTM(512 steps) -> FC(32->2)
//   K1 build_ptab: ptab[v] = (emb[v] @ w_ih^T + b_ih + b_hh) * gate_scale
//      gate_scale folds log2e so the scan uses raw v_exp_f32 (exp2):
//      sigmoid rows (i,f,o): *-log2e ; tanh rows (g): *+2*log2e
//   K2 lstm_scan: 1 wave per batch element. lane l owns gates l and l+64.
//      - w_hh pinned in VGPRs via asm keep-alive (R1: compiler remat'd the
//        loads, VGPR_Count=44 -> per-step global reloads; must show ~110 now)
//      - half-swap via v_permlane32_swap (VALU) instead of ds_bpermute
//      - token-index register ring (depth 4 groups) so ds_read never stalls
//      - ptab gather prefetched 4 steps deep

#define LOG2E 1.44269504088896340736f

__device__ __forceinline__ float fast_rcp(float x) { return __builtin_amdgcn_rcpf(x); }
__device__ __forceinline__ float fast_exp2(float x) { return __builtin_amdgcn_exp2f(x); }

// sigmoid(x) with y = -x*log2e prefolded: 1/(1+2^y)
__device__ __forceinline__ float sig_from_y(float y) { return fast_rcp(1.0f + fast_exp2(y)); }
// tanh(x) with y = 2x*log2e prefolded: 1 - 2/(1+2^y)
__device__ __forceinline__ float tanh_from_y(float y) {
    return fmaf(-2.0f, fast_rcp(1.0f + fast_exp2(y)), 1.0f);
}

__device__ __forceinline__ float lane_bcast(float v, int srclane) {
    return __uint_as_float(__builtin_amdgcn_readlane(__float_as_uint(v), srclane));
}

// broadcast the HIGH 32 lanes' values to lanes 0..31 (lanes>=32 get don't-care)
__device__ __forceinline__ float bcast_hi(float x) {
#if __has_builtin(__builtin_amdgcn_permlane32_swap)
    typedef unsigned uv2 __attribute__((ext_vector_type(2)));
    uv2 r = __builtin_amdgcn_permlane32_swap(__float_as_uint(x), __float_as_uint(x),
                                             false, false);
    return __uint_as_float(r.y);  // r.y = {x.hi, x.hi}
#else
    return __shfl_xor(x, 32, 64);  // lanes<32 receive hi half — same contract
#endif
}

// ---------------- K1: projected + prescaled embedding table ----------------
__global__ __launch_bounds__(64, 1) void build_ptab(
    const float4* __restrict__ emb4, const float4* __restrict__ wih4,
    const float* __restrict__ bih, const float* __restrict__ bhh,
    float2* __restrict__ ptab, int nrows) {
    const int lane = threadIdx.x;

    float w0[32], w1[32];
#pragma unroll
    for (int q = 0; q < 8; ++q) {
        float4 a = wih4[lane * 8 + q];
        float4 b = wih4[(lane + 64) * 8 + q];
        w0[4 * q + 0] = a.x; w0[4 * q + 1] = a.y; w0[4 * q + 2] = a.z; w0[4 * q + 3] = a.w;
        w1[4 * q + 0] = b.x; w1[4 * q + 1] = b.y; w1[4 * q + 2] = b.z; w1[4 * q + 3] = b.w;
    }
    const float bias0 = bih[lane] + bhh[lane];
    const float bias1 = bih[lane + 64] + bhh[lane + 64];
    const float s0 = -LOG2E;                                   // rows l: i,f -> sigmoid
    const float s1 = (lane < 32) ? (2.0f * LOG2E) : (-LOG2E);  // rows l+64: g -> tanh, o -> sigmoid

    for (int v = blockIdx.x; v < nrows; v += gridDim.x) {
        float a0 = bias0, a1 = bias1;
#pragma unroll
        for (int q = 0; q < 8; ++q) {
            float4 e = emb4[v * 8 + q];  // wave-uniform -> broadcast from cache
            a0 = fmaf(e.x, w0[4 * q + 0], a0);
            a0 = fmaf(e.y, w0[4 * q + 1], a0);
            a0 = fmaf(e.z, w0[4 * q + 2], a0);
            a0 = fmaf(e.w, w0[4 * q + 3], a0);
            a1 = fmaf(e.x, w1[4 * q + 0], a1);
            a1 = fmaf(e.y, w1[4 * q + 1], a1);
            a1 = fmaf(e.z, w1[4 * q + 2], a1);
            a1 = fmaf(e.w, w1[4 * q + 3], a1);
        }
        ptab[v * 64 + lane] = make_float2(a0 * s0, a1 * s1);  // coalesced 512B/row
    }
}

// ---------------- K2: LSTM scan, one wave per batch element ----------------
template <bool PTAB>
__global__ __launch_bounds__(64, 1) void lstm_scan(
    const int* __restrict__ x,
    const float2* __restrict__ ptab,
    const float* __restrict__ emb,
    const float* __restrict__ wih,
    const float* __restrict__ bih,
    const float* __restrict__ bhh,
    const float* __restrict__ whh,
    const float* __restrict__ fcw,
    const float* __restrict__ fcb,
    float* __restrict__ out,
    int S) {
    extern __shared__ int xrow[];
    const int b = blockIdx.x;
    const int lane = threadIdx.x;

    // token ids in LDS, padded so the prefetch ring never reads OOB
    for (int i = lane; i < S + 16; i += 64) xrow[i] = (i < S) ? x[(size_t)b * S + i] : 0;
    __syncthreads();

    const float s0 = -LOG2E;
    const float s1 = (lane < 32) ? (2.0f * LOG2E) : (-LOG2E);

    // recurrent weights: lane l holds w_hh rows l and l+64, prescaled, PINNED in VGPRs
    float w0[32], w1[32];
    {
        const float4* whh4 = (const float4*)whh;
#pragma unroll
        for (int q = 0; q < 8; ++q) {
            float4 a = whh4[lane * 8 + q];
            float4 bb = whh4[(lane + 64) * 8 + q];
            w0[4 * q + 0] = a.x * s0; w0[4 * q + 1] = a.y * s0;
            w0[4 * q + 2] = a.z * s0; w0[4 * q + 3] = a.w * s0;
            w1[4 * q + 0] = bb.x * s1; w1[4 * q + 1] = bb.y * s1;
            w1[4 * q + 2] = bb.z * s1; w1[4 * q + 3] = bb.w * s1;
        }
    }
#pragma unroll
    for (int j = 0; j < 32; ++j) {
        asm volatile("" : "+v"(w0[j]), "+v"(w1[j]));  // block rematerialization (R1 bug)
    }

    float h = 0.0f, c = 0.0f;

    // one LSTM step; g0,g1 are this lane's two prescaled gate pre-activations
    auto STEP = [&](float g0, float g1) {
        // gates += h @ w_hh^T (prescaled); 4-way split accumulators for ILP
        float x0 = g0, x1 = 0.f, x2 = 0.f, x3 = 0.f;
        float y0 = g1, y1 = 0.f, y2 = 0.f, y3 = 0.f;
#pragma unroll
        for (int j = 0; j < 32; j += 4) {
            float h0 = lane_bcast(h, j + 0);
            float h1 = lane_bcast(h, j + 1);
            float h2 = lane_bcast(h, j + 2);
            float h3 = lane_bcast(h, j + 3);
            x0 = fmaf(h0, w0[j + 0], x0); y0 = fmaf(h0, w1[j + 0], y0);
            x1 = fmaf(h1, w0[j + 1], x1); y1 = fmaf(h1, w1[j + 1], y1);
            x2 = fmaf(h2, w0[j + 2], x2); y2 = fmaf(h2, w1[j + 2], y2);
            x3 = fmaf(h3, w0[j + 3], x3); y3 = fmaf(h3, w1[j + 3], y3);
        }
        float a0 = (x0 + x1) + (x2 + x3);  // lanes<32: y_i ; lanes>=32: y_f
        float a1 = (y0 + y1) + (y2 + y3);  // lanes<32: y_g ; lanes>=32: y_o
        float b0 = bcast_hi(a0);           // lanes<32: y_f
        float b1 = bcast_hi(a1);           // lanes<32: y_o
        // lanes 0..31 compute the real update; lanes 32..63 bounded garbage (never read)
        float ig = sig_from_y(a0);
        float fg = sig_from_y(b0);
        float gg = tanh_from_y(a1);
        float og = sig_from_y(b1);
        c = fmaf(fg, c, ig * gg);
        h = og * tanh_from_y(c * (2.0f * LOG2E));
    };

    if (PTAB) {
        if (S >= 8) {
            // idx ring i0..i3 = tokens for steps t+4..t+7; p ring = steps t..t+3
            int i0 = xrow[4], i1 = xrow[5], i2 = xrow[6], i3 = xrow[7];
            float2 p0 = ptab[(size_t)xrow[0] * 64 + lane];
            float2 p1 = ptab[(size_t)xrow[1] * 64 + lane];
            float2 p2 = ptab[(size_t)xrow[2] * 64 + lane];
            float2 p3 = ptab[(size_t)xrow[3] * 64 + lane];
            int t = 0;
            for (; t + 8 <= S; t += 4) {
                STEP(p0.x, p0.y); p0 = ptab[(size_t)i0 * 64 + lane]; i0 = xrow[t + 8];
                STEP(p1.x, p1.y); p1 = ptab[(size_t)i1 * 64 + lane]; i1 = xrow[t + 9];
                STEP(p2.x, p2.y); p2 = ptab[(size_t)i2 * 64 + lane]; i2 = xrow[t + 10];
                STEP(p3.x, p3.y); p3 = ptab[(size_t)i3 * 64 + lane]; i3 = xrow[t + 11];
            }
            // remaining steps t..S-1 (ring holds t..t+3; i ring covers t+4..t+6)
            if (t + 0 < S) STEP(p0.x, p0.y);
            if (t + 1 < S) STEP(p1.x, p1.y);
            if (t + 2 < S) STEP(p2.x, p2.y);
            if (t + 3 < S) STEP(p3.x, p3.y);
            if (t + 4 < S) { float2 q = ptab[(size_t)i0 * 64 + lane]; STEP(q.x, q.y); }
            if (t + 5 < S) { float2 q = ptab[(size_t)i1 * 64 + lane]; STEP(q.x, q.y); }
            if (t + 6 < S) { float2 q = ptab[(size_t)i2 * 64 + lane]; STEP(q.x, q.y); }
        } else {
            for (int t = 0; t < S; ++t) {
                float2 q = ptab[(size_t)xrow[t] * 64 + lane];
                STEP(q.x, q.y);
            }
        }
    } else {
        // fallback: compute input projection on the fly (workspace too small)
        float wi0[32], wi1[32];
        {
            const float4* wih4 = (const float4*)wih;
#pragma unroll
            for (int q = 0; q < 8; ++q) {
                float4 a = wih4[lane * 8 + q];
                float4 bb = wih4[(lane + 64) * 8 + q];
                wi0[4 * q + 0] = a.x * s0; wi0[4 * q + 1] = a.y * s0;
                wi0[4 * q + 2] = a.z * s0; wi0[4 * q + 3] = a.w * s0;
                wi1[4 * q + 0] = bb.x * s1; wi1[4 * q + 1] = bb.y * s1;
                wi1[4 * q + 2] = bb.z * s1; wi1[4 * q + 3] = bb.w * s1;
            }
        }
        const float bias0 = (bih[lane] + bhh[lane]) * s0;
        const float bias1 = (bih[lane + 64] + bhh[lane + 64]) * s1;
        const float4* emb4 = (const float4*)emb;

        float4 eA[8], eB[8];
        auto LOADE = [&](int tt, float4* e) {
            int idx = xrow[(tt < S) ? tt : 0];
#pragma unroll
            for (int q = 0; q < 8; ++q) e[q] = emb4[idx * 8 + q];
        };
        auto STEPE = [&](const float4* e) {
            float a0 = bias0, a1 = bias1;
#pragma unroll
            for (int q = 0; q < 8; ++q) {
                a0 = fmaf(e[q].x, wi0[4 * q + 0], a0);
                a0 = fmaf(e[q].y, wi0[4 * q + 1], a0);
                a0 = fmaf(e[q].z, wi0[4 * q + 2], a0);
                a0 = fmaf(e[q].w, wi0[4 * q + 3], a0);
                a1 = fmaf(e[q].x, wi1[4 * q + 0], a1);
                a1 = fmaf(e[q].y, wi1[4 * q + 1], a1);
                a1 = fmaf(e[q].z, wi1[4 * q + 2], a1);
                a1 = fmaf(e[q].w, wi1[4 * q + 3], a1);
            }
            STEP(a0, a1);
        };
        LOADE(0, eA);
        int t = 0;
        for (; t + 2 <= S; t += 2) {
            LOADE(t + 1, eB);
            STEPE(eA);
            LOADE(t + 2, eA);
            STEPE(eB);
        }
        if (t < S) STEPE(eA);
    }

    // FC: out[b][n] = sum_k h_k * fc_w[n][k] + fc_b[n]; h valid in lanes 0..31
    float wv0 = fcw[lane & 31];
    float wv1 = fcw[32 + (lane & 31)];
    float p0v = (lane < 32) ? h * wv0 : 0.0f;
    float p1v = (lane < 32) ? h * wv1 : 0.0f;
#pragma unroll
    for (int m = 32; m >= 1; m >>= 1) {
        p0v += __shfl_xor(p0v, m, 64);
        p1v += __shfl_xor(p1v, m, 64);
    }
    if (lane == 0) {
        out[b * 2 + 0] = p0v + fcb[0];
        out[b * 2 + 1] = p1v + fcb[1];
    }
}

extern "C" void kernel_launch(void* const* d_in, const int* in_sizes, int n_in,
                              void* d_out, int out_size, void* d_ws, size_t ws_size,
                              hipStream_t stream) {
    const int* x = (const int*)d_in[0];
    const float* emb = (const float*)d_in[1];
    const float* wih = (const float*)d_in[2];
    const float* whh = (const float*)d_in[3];
    const float* bih = (const float*)d_in[4];
    const float* bhh = (const float*)d_in[5];
    const float* fcw = (const float*)d_in[6];
    const float* fcb = (const float*)d_in[7];
    float* out = (float*)d_out;

    const int B = out_size / 2;          // 1024
    const int S = in_sizes[0] / B;       // 512
    const int nrows = in_sizes[1] / 32;  // 50001 (EMB=32)

    const size_t need = (size_t)nrows * 64 * sizeof(float2);  // 25.6 MB
    const size_t smem = (size_t)(S + 16) * sizeof(int);

    if (ws_size >= need) {
        float2* ptab = (float2*)d_ws;
        int nb = nrows < 2048 ? nrows : 2048;
        build_ptab<<<nb, 64, 0, stream>>>((const float4*)emb, (const float4*)wih,
                                          bih, bhh, ptab, nrows);
        lstm_scan<true><<<B, 64, smem, stream>>>(x, ptab, emb, wih, bih, bhh, whh,
                                                 fcw, fcb, out, S);
    } else {
        lstm_scan<false><<<B, 64, smem, stream>>>(x, nullptr, emb, wih, bih, bhh, whh,
                                                  fcw, fcb, out, S);
    }
}

// Round 3
// 151.413 us; speedup vs baseline: 1.5664x; 1.1572x over previous
//
#include <hip/hip_runtime.h>

// LSTM text classifier: emb-gather -> LSTM(512 steps) -> FC(32->2)
//   K1 build_ptab: ptab[v] = (emb[v] @ w_ih^T + b_ih + b_hh) * gate_scale
//      (scales fold log2e so the scan uses raw v_exp_f32 / exp2)
//   K2 lstm_scan: 1 wave per batch element. lane l owns gates l and l+64.
//   R3: STEP is a MACRO (R2's by-ref lambda address-took the weight arrays ->
//       SROA failure -> weights lived in scratch, ~64 scratch loads/step,
//       VGPR_Count=48). Weights now ext_vector_type(32) SSA values with
//       compile-time indices only -> must be VGPR-resident (expect ~130 VGPRs).

#define LOG2E 1.44269504088896340736f

typedef float f32x32 __attribute__((ext_vector_type(32)));

__device__ __forceinline__ float fast_rcp(float x) { return __builtin_amdgcn_rcpf(x); }
__device__ __forceinline__ float fast_exp2(float x) { return __builtin_amdgcn_exp2f(x); }

__device__ __forceinline__ float lane_bcast(float v, int srclane) {
    return __uint_as_float(__builtin_amdgcn_readlane(__float_as_uint(v), srclane));
}

// broadcast the HIGH 32 lanes' values to lanes 0..31 (lanes>=32 get don't-care)
// byte-identical to R2 (verified: absmax 0.0) — do not touch.
__device__ __forceinline__ float bcast_hi(float x) {
#if __has_builtin(__builtin_amdgcn_permlane32_swap)
    typedef unsigned uv2 __attribute__((ext_vector_type(2)));
    uv2 r = __builtin_amdgcn_permlane32_swap(__float_as_uint(x), __float_as_uint(x),
                                             false, false);
    return __uint_as_float(r.y);  // hi-half value delivered to lanes 0..31
#else
    return __shfl_xor(x, 32, 64);
#endif
}

// ---------------- K1: projected + prescaled embedding table ----------------
__global__ __launch_bounds__(64, 1) void build_ptab(
    const float4* __restrict__ emb4, const float4* __restrict__ wih4,
    const float* __restrict__ bih, const float* __restrict__ bhh,
    float2* __restrict__ ptab, int nrows) {
    const int lane = threadIdx.x;

    f32x32 w0, w1;
#pragma unroll
    for (int q = 0; q < 8; ++q) {
        float4 a = wih4[lane * 8 + q];
        float4 b = wih4[(lane + 64) * 8 + q];
        w0[4 * q + 0] = a.x; w0[4 * q + 1] = a.y; w0[4 * q + 2] = a.z; w0[4 * q + 3] = a.w;
        w1[4 * q + 0] = b.x; w1[4 * q + 1] = b.y; w1[4 * q + 2] = b.z; w1[4 * q + 3] = b.w;
    }
    const float bias0 = bih[lane] + bhh[lane];
    const float bias1 = bih[lane + 64] + bhh[lane + 64];
    const float s0 = -LOG2E;                                   // rows l: i,f -> sigmoid
    const float s1 = (lane < 32) ? (2.0f * LOG2E) : (-LOG2E);  // rows l+64: g tanh / o sigmoid

    for (int v = blockIdx.x; v < nrows; v += gridDim.x) {
        float a0 = bias0, a1 = bias1;
#pragma unroll
        for (int q = 0; q < 8; ++q) {
            float4 e = emb4[v * 8 + q];  // wave-uniform -> cache broadcast
            a0 = fmaf(e.x, w0[4 * q + 0], a0);
            a0 = fmaf(e.y, w0[4 * q + 1], a0);
            a0 = fmaf(e.z, w0[4 * q + 2], a0);
            a0 = fmaf(e.w, w0[4 * q + 3], a0);
            a1 = fmaf(e.x, w1[4 * q + 0], a1);
            a1 = fmaf(e.y, w1[4 * q + 1], a1);
            a1 = fmaf(e.z, w1[4 * q + 2], a1);
            a1 = fmaf(e.w, w1[4 * q + 3], a1);
        }
        ptab[v * 64 + lane] = make_float2(a0 * s0, a1 * s1);  // coalesced 512B/row
    }
}

// one LSTM step; G0,G1 are this lane's two prescaled gate pre-activations.
// Uses kernel-scope h, c, wf0, wf1. All indices compile-time.
#define STEP(G0, G1)                                                          \
    do {                                                                      \
        float _x0 = (G0), _x1 = 0.f, _x2 = 0.f, _x3 = 0.f;                    \
        float _y0 = (G1), _y1 = 0.f, _y2 = 0.f, _y3 = 0.f;                    \
        _Pragma("unroll") for (int _j = 0; _j < 32; _j += 4) {                \
            float _h0 = lane_bcast(h, _j + 0);                                \
            float _h1 = lane_bcast(h, _j + 1);                                \
            float _h2 = lane_bcast(h, _j + 2);                                \
            float _h3 = lane_bcast(h, _j + 3);                                \
            _x0 = fmaf(_h0, wf0[_j + 0], _x0);                                \
            _y0 = fmaf(_h0, wf1[_j + 0], _y0);                                \
            _x1 = fmaf(_h1, wf0[_j + 1], _x1);                                \
            _y1 = fmaf(_h1, wf1[_j + 1], _y1);                                \
            _x2 = fmaf(_h2, wf0[_j + 2], _x2);                                \
            _y2 = fmaf(_h2, wf1[_j + 2], _y2);                                \
            _x3 = fmaf(_h3, wf0[_j + 3], _x3);                                \
            _y3 = fmaf(_h3, wf1[_j + 3], _y3);                                \
        }                                                                     \
        float _a0 = (_x0 + _x1) + (_x2 + _x3); /* lo: y_i*s0, hi: y_f*s0 */   \
        float _a1 = (_y0 + _y1) + (_y2 + _y3); /* lo: y_g*s1, hi: y_o*s1 */   \
        float _sg = fast_rcp(1.0f + fast_exp2(_a0)); /* lo: i, hi: f */       \
        float _r1 = fast_rcp(1.0f + fast_exp2(_a1)); /* hi: o */              \
        float _fg = bcast_hi(_sg);                                            \
        float _og = bcast_hi(_r1);                                            \
        float _gg = fmaf(-2.0f, _r1, 1.0f); /* lo: tanh(g) */                 \
        c = fmaf(_fg, c, _sg * _gg);                                          \
        float _e2 = fast_exp2(c * (2.0f * LOG2E));                            \
        h = _og * fmaf(-2.0f, fast_rcp(1.0f + _e2), 1.0f);                    \
    } while (0)

// ---------------- K2: LSTM scan, one wave per batch element ----------------
template <bool PTAB>
__global__ __launch_bounds__(64, 1) void lstm_scan(
    const int* __restrict__ x,
    const float2* __restrict__ ptab,
    const float* __restrict__ emb,
    const float* __restrict__ wih,
    const float* __restrict__ bih,
    const float* __restrict__ bhh,
    const float* __restrict__ whh,
    const float* __restrict__ fcw,
    const float* __restrict__ fcb,
    float* __restrict__ out,
    int S) {
    extern __shared__ int xrow[];
    const int b = blockIdx.x;
    const int lane = threadIdx.x;

    // token ids in LDS, padded so the prefetch ring never reads OOB
    for (int i = lane; i < S + 16; i += 64) xrow[i] = (i < S) ? x[(size_t)b * S + i] : 0;
    __syncthreads();

    const float s0 = -LOG2E;
    const float s1 = (lane < 32) ? (2.0f * LOG2E) : (-LOG2E);

    // recurrent weights: lane l holds prescaled w_hh rows l and l+64 as SSA vectors
    f32x32 wf0, wf1;
    {
        const float4* whh4 = (const float4*)whh;
#pragma unroll
        for (int q = 0; q < 8; ++q) {
            float4 a = whh4[lane * 8 + q];
            float4 bb = whh4[(lane + 64) * 8 + q];
            wf0[4 * q + 0] = a.x * s0; wf0[4 * q + 1] = a.y * s0;
            wf0[4 * q + 2] = a.z * s0; wf0[4 * q + 3] = a.w * s0;
            wf1[4 * q + 0] = bb.x * s1; wf1[4 * q + 1] = bb.y * s1;
            wf1[4 * q + 2] = bb.z * s1; wf1[4 * q + 3] = bb.w * s1;
        }
    }

    float h = 0.0f, c = 0.0f;

    if constexpr (PTAB) {
        // p ring = pre-activations for steps t..t+3; i ring = tokens t+4..t+7
        int i0 = xrow[4], i1 = xrow[5], i2 = xrow[6], i3 = xrow[7];
        float2 p0 = ptab[(size_t)xrow[0] * 64 + lane];
        float2 p1 = ptab[(size_t)xrow[1] * 64 + lane];
        float2 p2 = ptab[(size_t)xrow[2] * 64 + lane];
        float2 p3 = ptab[(size_t)xrow[3] * 64 + lane];
        int t = 0;
        for (; t + 8 <= S; t += 4) {
            STEP(p0.x, p0.y); p0 = ptab[(size_t)i0 * 64 + lane]; i0 = xrow[t + 8];
            STEP(p1.x, p1.y); p1 = ptab[(size_t)i1 * 64 + lane]; i1 = xrow[t + 9];
            STEP(p2.x, p2.y); p2 = ptab[(size_t)i2 * 64 + lane]; i2 = xrow[t + 10];
            STEP(p3.x, p3.y); p3 = ptab[(size_t)i3 * 64 + lane]; i3 = xrow[t + 11];
        }
        if (t + 0 < S) STEP(p0.x, p0.y);
        if (t + 1 < S) STEP(p1.x, p1.y);
        if (t + 2 < S) STEP(p2.x, p2.y);
        if (t + 3 < S) STEP(p3.x, p3.y);
        if (t + 4 < S) { float2 q = ptab[(size_t)i0 * 64 + lane]; STEP(q.x, q.y); }
        if (t + 5 < S) { float2 q = ptab[(size_t)i1 * 64 + lane]; STEP(q.x, q.y); }
        if (t + 6 < S) { float2 q = ptab[(size_t)i2 * 64 + lane]; STEP(q.x, q.y); }
    } else {
        // fallback: on-the-fly input projection (workspace too small); cold path
        f32x32 wi0, wi1;
        {
            const float4* wih4 = (const float4*)wih;
#pragma unroll
            for (int q = 0; q < 8; ++q) {
                float4 a = wih4[lane * 8 + q];
                float4 bb = wih4[(lane + 64) * 8 + q];
                wi0[4 * q + 0] = a.x * s0; wi0[4 * q + 1] = a.y * s0;
                wi0[4 * q + 2] = a.z * s0; wi0[4 * q + 3] = a.w * s0;
                wi1[4 * q + 0] = bb.x * s1; wi1[4 * q + 1] = bb.y * s1;
                wi1[4 * q + 2] = bb.z * s1; wi1[4 * q + 3] = bb.w * s1;
            }
        }
        const float bias0 = (bih[lane] + bhh[lane]) * s0;
        const float bias1 = (bih[lane + 64] + bhh[lane + 64]) * s1;
        const float4* emb4 = (const float4*)emb;
        for (int t = 0; t < S; ++t) {
            int idx = xrow[t];
            float a0 = bias0, a1 = bias1;
#pragma unroll
            for (int q = 0; q < 8; ++q) {
                float4 e = emb4[(size_t)idx * 8 + q];
                a0 = fmaf(e.x, wi0[4 * q + 0], a0);
                a0 = fmaf(e.y, wi0[4 * q + 1], a0);
                a0 = fmaf(e.z, wi0[4 * q + 2], a0);
                a0 = fmaf(e.w, wi0[4 * q + 3], a0);
                a1 = fmaf(e.x, wi1[4 * q + 0], a1);
                a1 = fmaf(e.y, wi1[4 * q + 1], a1);
                a1 = fmaf(e.z, wi1[4 * q + 2], a1);
                a1 = fmaf(e.w, wi1[4 * q + 3], a1);
            }
            STEP(a0, a1);
        }
    }

    // FC: out[b][n] = sum_k h_k * fc_w[n][k] + fc_b[n]; h valid in lanes 0..31
    float wv0 = fcw[lane & 31];
    float wv1 = fcw[32 + (lane & 31)];
    float p0v = (lane < 32) ? h * wv0 : 0.0f;
    float p1v = (lane < 32) ? h * wv1 : 0.0f;
#pragma unroll
    for (int m = 32; m >= 1; m >>= 1) {
        p0v += __shfl_xor(p0v, m, 64);
        p1v += __shfl_xor(p1v, m, 64);
    }
    if (lane == 0) {
        out[b * 2 + 0] = p0v + fcb[0];
        out[b * 2 + 1] = p1v + fcb[1];
    }
}

extern "C" void kernel_launch(void* const* d_in, const int* in_sizes, int n_in,
                              void* d_out, int out_size, void* d_ws, size_t ws_size,
                              hipStream_t stream) {
    const int* x = (const int*)d_in[0];
    const float* emb = (const float*)d_in[1];
    const float* wih = (const float*)d_in[2];
    const float* whh = (const float*)d_in[3];
    const float* bih = (const float*)d_in[4];
    const float* bhh = (const float*)d_in[5];
    const float* fcw = (const float*)d_in[6];
    const float* fcb = (const float*)d_in[7];
    float* out = (float*)d_out;

    const int B = out_size / 2;          // 1024
    const int S = in_sizes[0] / B;       // 512
    const int nrows = in_sizes[1] / 32;  // 50001 (EMB=32)

    const size_t need = (size_t)nrows * 64 * sizeof(float2);  // 25.6 MB
    const size_t smem = (size_t)(S + 16) * sizeof(int);

    if (ws_size >= need) {
        float2* ptab = (float2*)d_ws;
        int nb = nrows < 4096 ? nrows : 4096;
        build_ptab<<<nb, 64, 0, stream>>>((const float4*)emb, (const float4*)wih,
                                          bih, bhh, ptab, nrows);
        lstm_scan<true><<<B, 64, smem, stream>>>(x, ptab, emb, wih, bih, bhh, whh,
                                                 fcw, fcb, out, S);
    } else {
        lstm_scan<false><<<B, 64, smem, stream>>>(x, nullptr, emb, wih, bih, bhh, whh,
                                                  fcw, fcb, out, S);
    }
}